// Round 6
// baseline (40.391 us; speedup 1.0000x reference)
//
#include <hip/hip_runtime.h>
#include <hip/hip_bf16.h>
#include <math.h>

#define N_Q 2048
#define M_K 1024
#define DIN 128
#define DK  64
#define NBLK 256

typedef __attribute__((ext_vector_type(8))) short short8;
typedef __attribute__((ext_vector_type(4))) float f32x4;
typedef __attribute__((ext_vector_type(4))) unsigned int u32x4;

// bf16 hi/lo split of an fp32 value, packed into one dword (hi in low 16)
static __device__ __forceinline__ unsigned int pack_split(float v)
{
    __hip_bfloat16 hb = __float2bfloat16(v);
    float hf = __bfloat162float(hb);
    __hip_bfloat16 lb = __float2bfloat16(v - hf);
    return (unsigned int)(*(unsigned short*)&hb)
         | ((unsigned int)(*(unsigned short*)&lb) << 16);
}

// unpack 8 packed u32 (8 k-elems) -> hi short8 + lo short8 (bf16 bit patterns)
static __device__ __forceinline__ void unpack8(const unsigned int* p,
                                               short8& h, short8& l)
{
    u32x4 a = *(const u32x4*)p;
    u32x4 b = *(const u32x4*)(p + 4);
    u32x4 hu, lu;
    hu.x = (a.x & 0xFFFFu) | (a.y << 16);
    hu.y = (a.z & 0xFFFFu) | (a.w << 16);
    hu.z = (b.x & 0xFFFFu) | (b.y << 16);
    hu.w = (b.z & 0xFFFFu) | (b.w << 16);
    lu.x = (a.x >> 16) | (a.y & 0xFFFF0000u);
    lu.y = (a.z >> 16) | (a.w & 0xFFFF0000u);
    lu.z = (b.x >> 16) | (b.y & 0xFFFF0000u);
    lu.w = (b.z >> 16) | (b.w & 0xFFFF0000u);
    union { u32x4 u; short8 s; } ch, cl;
    ch.u = hu; cl.u = lu;
    h = ch.s; l = cl.s;
}

// ---------------------------------------------------------------------------
// Single fused kernel: 256 blocks x 512 thr (8 waves), 1 block/CU, all
// co-resident -> hand-rolled grid barrier is deadlock-free.
// Phase 1: wave w computes q-row bid*8+w AND k-row (bid&127)*8+w (k rows
//   duplicated across block pairs -> bitwise-identical benign dup stores).
//   Q split+norm stay in LDS (block-local); K split+norm go to global ws.
// Barrier: __threadfence (wbl2) + agent-scope atomic arrive/spin (ctr
//   zeroed by a hipMemsetAsync node each launch).
// Phase 2: R5-validated MFMA score at 8 q-rows/block: 16x16x32 bf16 tiles
//   with A rows duplicated (c&7); split-bf16 fp32 emulation (hh+hl+lh);
//   g<2 lanes own the real rows for reductions/stores.
// ---------------------------------------------------------------------------
__global__ __launch_bounds__(512) void fused_kernel(
    const float* __restrict__ q, const float* __restrict__ k,
    const float* __restrict__ W,
    unsigned int* __restrict__ Khl, float* __restrict__ kn2,
    unsigned int* __restrict__ ctr, float* __restrict__ out)
{
    __shared__ float W_lds[DK][DIN + 4];      // 33.8 KB, stride 132
    __shared__ float row_lds[8][2][DIN];      // 8 KB: [wave][q|k][dim]
    __shared__ unsigned int qhl_lds[8][DK];   // 2 KB packed Q split
    __shared__ float qn2_lds[8];
    __shared__ float redmax[8][8];
    __shared__ float redsum[8][8];

    const int tx = threadIdx.x;
    const int w = tx >> 6, lane = tx & 63;
    const int bid = blockIdx.x;

    // ---------------- phase 1: projections ----------------
    const float4* W4 = (const float4*)W;
    #pragma unroll
    for (int i = 0; i < 4; ++i) {
        int idx = tx + i * 512;               // float4 index, 0..2047
        float4 v = W4[idx];
        *(float4*)&W_lds[idx >> 5][(idx & 31) * 4] = v;
    }

    const int qrow = bid * 8 + w;             // 0..2047
    const int krow = (bid & 127) * 8 + w;     // 0..1023 (dup across block pairs)
    {
        const float* qs = q + (size_t)qrow * DIN;
        const float* ks = k + (size_t)krow * DIN;
        row_lds[w][0][lane]      = qs[lane];
        row_lds[w][0][lane + 64] = qs[lane + 64];
        row_lds[w][1][lane]      = ks[lane];
        row_lds[w][1][lane + 64] = ks[lane + 64];
    }
    __syncthreads();                          // W_lds ready (row_lds wave-local)

    float aq = 0.f, ak = 0.f;                 // lane = output dim
    #pragma unroll
    for (int d = 0; d < DIN; d += 4) {
        float4 wv = *(const float4*)&W_lds[lane][d];
        float4 rq = *(const float4*)&row_lds[w][0][d];
        float4 rk = *(const float4*)&row_lds[w][1][d];
        aq = fmaf(wv.x, rq.x, aq); aq = fmaf(wv.y, rq.y, aq);
        aq = fmaf(wv.z, rq.z, aq); aq = fmaf(wv.w, rq.w, aq);
        ak = fmaf(wv.x, rk.x, ak); ak = fmaf(wv.y, rk.y, ak);
        ak = fmaf(wv.z, rk.z, ak); ak = fmaf(wv.w, rk.w, ak);
    }

    float sqq = aq * aq, sqk = ak * ak;
    #pragma unroll
    for (int off = 32; off >= 1; off >>= 1) {
        sqq += __shfl_xor(sqq, off, 64);
        sqk += __shfl_xor(sqk, off, 64);
    }

    qhl_lds[w][lane] = pack_split(aq);
    if (lane == 0) qn2_lds[w] = sqq;
    Khl[(size_t)krow * DK + lane] = pack_split(ak);
    if (lane == 0) kn2[krow] = sqk;

    // ---------------- grid barrier ----------------
    __syncthreads();   // drains vmcnt -> block's global stores are in L2
    if (tx == 0) {
        __threadfence();                      // write back L2 (device scope)
        __hip_atomic_fetch_add(ctr, 1u, __ATOMIC_ACQ_REL, __HIP_MEMORY_SCOPE_AGENT);
        while (__hip_atomic_load(ctr, __ATOMIC_ACQUIRE, __HIP_MEMORY_SCOPE_AGENT)
               < (unsigned)NBLK)
            __builtin_amdgcn_s_sleep(8);
    }
    __syncthreads();

    // ---------------- phase 2: MFMA score + softmax ----------------
    const int g = lane >> 4, c = lane & 15;
    const int n0 = bid * 8;

    short8 Ah0, Al0, Ah1, Al1;
    unpack8(&qhl_lds[c & 7][g * 8],      Ah0, Al0);
    unpack8(&qhl_lds[c & 7][32 + g * 8], Ah1, Al1);

    float qn[4];
    #pragma unroll
    for (int j = 0; j < 4; ++j) qn[j] = qn2_lds[(4 * g + j) & 7];

    float s[8][4];
    #pragma unroll
    for (int t = 0; t < 8; ++t) {
        const int m = w * 128 + t * 16 + c;
        const unsigned int* kr = Khl + (size_t)m * DK;
        short8 Bh0, Bl0, Bh1, Bl1;
        unpack8(kr + g * 8, Bh0, Bl0);
        unpack8(kr + 32 + g * 8, Bh1, Bl1);

        f32x4 acc = {0.f, 0.f, 0.f, 0.f};
        acc = __builtin_amdgcn_mfma_f32_16x16x32_bf16(Ah0, Bh0, acc, 0, 0, 0);
        acc = __builtin_amdgcn_mfma_f32_16x16x32_bf16(Ah1, Bh1, acc, 0, 0, 0);
        acc = __builtin_amdgcn_mfma_f32_16x16x32_bf16(Ah0, Bl0, acc, 0, 0, 0);
        acc = __builtin_amdgcn_mfma_f32_16x16x32_bf16(Ah1, Bl1, acc, 0, 0, 0);
        acc = __builtin_amdgcn_mfma_f32_16x16x32_bf16(Al0, Bh0, acc, 0, 0, 0);
        acc = __builtin_amdgcn_mfma_f32_16x16x32_bf16(Al1, Bh1, acc, 0, 0, 0);

        const float kn = kn2[m];
        #pragma unroll
        for (int j = 0; j < 4; ++j) {
            float d2 = fmaxf(qn[j] + kn - 2.f * acc[j], 0.f);
            s[t][j] = -0.5f * sqrtf(d2);
        }
    }

    // row max (per 16-lane group over this wave's 128 cols, then cross-wave)
    #pragma unroll
    for (int j = 0; j < 4; ++j) {
        float m8 = s[0][j];
        #pragma unroll
        for (int t = 1; t < 8; ++t) m8 = fmaxf(m8, s[t][j]);
        m8 = fmaxf(m8, __shfl_xor(m8, 1, 64));
        m8 = fmaxf(m8, __shfl_xor(m8, 2, 64));
        m8 = fmaxf(m8, __shfl_xor(m8, 4, 64));
        m8 = fmaxf(m8, __shfl_xor(m8, 8, 64));
        if (c == 0 && g < 2) redmax[4 * g + j][w] = m8;
    }
    __syncthreads();

    float mx[4];
    #pragma unroll
    for (int j = 0; j < 4; ++j) {
        const float* rm = redmax[(4 * g + j) & 7];
        float m = rm[0];
        #pragma unroll
        for (int ww = 1; ww < 8; ++ww) m = fmaxf(m, rm[ww]);
        mx[j] = m;
    }

    // exp + row sum
    #pragma unroll
    for (int j = 0; j < 4; ++j) {
        float t8 = 0.f;
        #pragma unroll
        for (int t = 0; t < 8; ++t) {
            s[t][j] = __expf(s[t][j] - mx[j]);
            t8 += s[t][j];
        }
        t8 += __shfl_xor(t8, 1, 64);
        t8 += __shfl_xor(t8, 2, 64);
        t8 += __shfl_xor(t8, 4, 64);
        t8 += __shfl_xor(t8, 8, 64);
        if (c == 0 && g < 2) redsum[4 * g + j][w] = t8;
    }
    __syncthreads();

    if (g < 2) {
        float inv[4];
        #pragma unroll
        for (int j = 0; j < 4; ++j) {
            const float* rs = redsum[4 * g + j];
            float t = 0.f;
            #pragma unroll
            for (int ww = 0; ww < 8; ++ww) t += rs[ww];
            inv[j] = 1.0f / t;
        }
        #pragma unroll
        for (int t = 0; t < 8; ++t) {
            const int m = w * 128 + t * 16 + c;
            #pragma unroll
            for (int j = 0; j < 4; ++j)
                out[(size_t)(n0 + 4 * g + j) * M_K + m] = s[t][j] * inv[j];
        }
    }
}

extern "C" void kernel_launch(void* const* d_in, const int* in_sizes, int n_in,
                              void* d_out, int out_size, void* d_ws, size_t ws_size,
                              hipStream_t stream)
{
    const float* q = (const float*)d_in[0];
    const float* k = (const float*)d_in[1];
    const float* W = (const float*)d_in[2];
    float* out = (float*)d_out;

    // ws layout (bytes): Khl 256K @0 | kn2 4K @256K | ctr @512K (own line)
    unsigned char* base = (unsigned char*)d_ws;
    unsigned int* Khl = (unsigned int*)base;
    float* kn2 = (float*)(base + 262144);
    unsigned int* ctr = (unsigned int*)(base + 524288);

    hipMemsetAsync(ctr, 0, 4, stream);
    fused_kernel<<<NBLK, 512, 0, stream>>>(q, k, W, Khl, kn2, ctr, out);
}